// Round 8
// baseline (3575.348 us; speedup 1.0000x reference)
//
#include <hip/hip_runtime.h>

// Problem constants (must match reference)
#define Nb   256
#define Tt   2048
#define INs  6
#define HID  128
#define STs  64
#define LAY  134   // INs + HID
#define OUTs 6
#define NPAIR 67   // LAY/2
#define NDW  68    // padded dword count (f16x2 units); last dword is zero pad

typedef _Float16 h2 __attribute__((ext_vector_type(2)));
typedef __fp16  f16x2 __attribute__((ext_vector_type(2)));   // builtin-compatible spelling
typedef __fp16  f16x8 __attribute__((ext_vector_type(8)));   // 4 VGPRs; pair p = dword p

__device__ __forceinline__ float exp2_fast(float x) {
#if __has_builtin(__builtin_amdgcn_exp2f)
    return __builtin_amdgcn_exp2f(x);
#else
    return exp2f(x);
#endif
}
__device__ __forceinline__ float rcp_fast(float x) {
#if __has_builtin(__builtin_amdgcn_rcpf)
    return __builtin_amdgcn_rcpf(x);
#else
    return 1.0f / x;
#endif
}
// tanh(x) = 1 - 2/(exp2(2*log2e*x)+1); saturates correctly for |x| large
__device__ __forceinline__ float tanh_fast(float x) {
    float e = exp2_fast(x * 2.8853900817779268f);
    return 1.0f - 2.0f * rcp_fast(e + 1.0f);
}
__device__ __forceinline__ unsigned pack2(float a, float b) {
#if __has_builtin(__builtin_amdgcn_cvt_pkrtz)
    union { f16x2 h; unsigned u; } u;
    u.h = __builtin_amdgcn_cvt_pkrtz(a, b);
    return u.u;
#else
    union { h2 h; unsigned u; } u;
    u.h[0] = (_Float16)a; u.h[1] = (_Float16)b;
    return u.u;
#endif
}
// dot of packed-f16 activation dword with an f16x2 weight pair, f32 accumulate
__device__ __forceinline__ float dot2p(unsigned av, f16x2 wv, float c) {
    union { unsigned u; f16x2 f; } ua; ua.u = av;
#if __has_builtin(__builtin_amdgcn_fdot2)
    return __builtin_amdgcn_fdot2(ua.f, wv, c, false);   // v_dot2_f32_f16
#else
    return c + (float)ua.f[0] * (float)wv[0] + (float)ua.f[1] * (float)wv[1];
#endif
}

// ---- X-macro over the 17 weight vector registers (one column = 17 x f16x8) ----
#define WR17(M) M(0) M(1) M(2) M(3) M(4) M(5) M(6) M(7) M(8) M(9) M(10) M(11) M(12) M(13) M(14) M(15) M(16)

#define DECLW(k) f16x8 w##k = {};

// rows 8k..8k+7 of column j, stride od; rows >= LAY are zero pad (k==16 tail)
#define LOADW(k) { \
    f16x8 tmp; \
    _Pragma("unroll") \
    for (int q = 0; q < 8; ++q) { \
        int r = 8 * (k) + q; \
        float f = (r < LAY) ? Wp[r * od + j] : 0.f; \
        tmp[q] = (__fp16)f; \
    } \
    w##k = tmp; \
}

#define DOT4(k) { \
    uint4 v = b4[k]; \
    a0 = dot2p(v.x, __builtin_shufflevector(w##k, w##k, 0, 1), a0); \
    a1 = dot2p(v.y, __builtin_shufflevector(w##k, w##k, 2, 3), a1); \
    a2 = dot2p(v.z, __builtin_shufflevector(w##k, w##k, 4, 5), a2); \
    a3 = dot2p(v.w, __builtin_shufflevector(w##k, w##k, 6, 7), a3); \
}

#define DO_DOT(bufname, sres) { \
    const uint4* b4 = (const uint4*)(bufname); \
    float a0 = 0.f, a1 = 0.f, a2 = 0.f, a3 = 0.f; \
    WR17(DOT4) \
    sres = ((a0 + a1) + (a2 + a3)); \
}

// projection: out[0..5] = H . Wo[:,o] + bo; one wave, lane l owns H[2l],H[2l+1].
// Wo/bo live in LDS (Wol/bol) — keeps 18 per-thread constants out of the
// loop-live register set (liveness is path-insensitive across thread roles).
__device__ __forceinline__ void do_proj(const float* Hrow, const float* Wol,
                                        const float* bol, float* outp, int l) {
    float hA = Hrow[2*l], hB = Hrow[2*l+1];
    float r[6];
#pragma unroll
    for (int o = 0; o < 6; ++o)
        r[o] = hA * Wol[(2*l) * OUTs + o] + hB * Wol[(2*l + 1) * OUTs + o];
#pragma unroll
    for (int o = 0; o < 6; ++o) {
#pragma unroll
        for (int k = 1; k < 64; k <<= 1) r[o] += __shfl_xor(r[o], k, 64);
    }
    if (l == 0) {
#pragma unroll
        for (int o = 0; o < 6; ++o) outp[o] = r[o] + bol[o];
    }
}

// Thread roles (1024 threads, 16 waves). Pair (2j, 2j+1) owns column j of the
// phase's two matrices; product combined via __shfl_xor(.,1).
//   [0,268)    L1: Wg1[0] (even) / Wg2[0] (odd), col j = tid>>1
//   [320,588)  L2: Wg1[1] / Wg2[1], col j = (tid-320)>>1
//   [640,896)  AB: Wa (even, owns H[j]) / Wb (odd), col j = (tid-640)>>1
//   [896,960)  proj wave (P1 shadow)
//   1022       norm thread (P1 shadow);  1023: x-part writer (P2 shadow)
//
// OCCUPANCY PIN (rounds 6/7 post-mortem): the backend derives its occupancy
// target from LDS: 51 KB -> 2 blocks/CU -> 8 waves/EU -> VGPR cap 64 -> the
// 68-VGPR weight set spills to scratch. ldspad pushes LDS past 80 KB so only
// 1 block/CU fits -> 4 waves/EU target -> 128-VGPR budget. Grid is 256 blocks
// = 1 block/CU anyway, so nothing real is lost.
__global__ __launch_bounds__(1024) __attribute__((amdgpu_waves_per_eu(4, 4)))
void lmsc_kernel(const float* __restrict__ X,  const float* __restrict__ H0,
                 const float* __restrict__ Wg1, const float* __restrict__ bg1,
                 const float* __restrict__ Wg2, const float* __restrict__ bg2,
                 const float* __restrict__ Wa,  const float* __restrict__ ba,
                 const float* __restrict__ Wb,  const float* __restrict__ bb,
                 const float* __restrict__ Wh,  const float* __restrict__ bh,
                 const float* __restrict__ Wo,  const float* __restrict__ bo,
                 float* __restrict__ out)
{
    __shared__ float Xls[Tt * INs];                 // 48 KB: this row's whole input
    __shared__ float ldspad[8192];                  // 32 KB: occupancy pin (see above)
    __shared__ alignas(16) unsigned LvX[NDW];       // step input:  [x/n (3dw) | H f16 | pad]
    __shared__ alignas(16) unsigned LvB[NDW];       // after layer 1
    __shared__ alignas(16) unsigned LvC[NDW];       // after layer 2
    __shared__ float Hf[HID];                       // f32 H copy for projection
    __shared__ float H0l[STs];
    __shared__ float Wol[HID * OUTs];               // 3 KB: Wo staged for proj wave
    __shared__ float bol[OUTs];
    __shared__ float nrm[2], rnr[2];

    const int tid = threadIdx.x;
    const int n   = blockIdx.x;

    // keep ldspad allocated without doing work (rule #17: empty-asm liveness)
    {
        unsigned lp = (unsigned)(unsigned long long)&ldspad[tid];
        asm volatile("" :: "v"(lp));
    }

    const bool isL1 = tid < 268;
    const bool isL2 = (tid >= 320) & (tid < 588);
    const bool isAB = (tid >= 640) & (tid < 896);
    const bool isPJ = (tid >= 896) & (tid < 960);

    // ---------------- stage X row (coalesced float4) ----------------
    {
        const float4* Xg  = (const float4*)(X + (size_t)n * (Tt * INs));
        float4*       Xl4 = (float4*)Xls;
        for (int i = tid; i < (Tt * INs) / 4; i += 1024) Xl4[i] = Xg[i];
    }
    if (tid < STs) H0l[tid] = H0[n * STs + tid];
    if (tid < HID * OUTs) Wol[tid] = Wo[tid];
    if (tid >= 1000 && tid < 1000 + OUTs) bol[tid - 1000] = bo[tid - 1000];
    if (tid == 1021) { LvX[NDW-1] = 0u; LvB[NDW-1] = 0u; LvC[NDW-1] = 0u; }

    // ------- weight column -> 17 NAMED f16x8 vector registers (SSA, no alloca) -------
    WR17(DECLW)
    float bias = 0.f;
    {
        const float* Wp = nullptr; int od = LAY, j = 0;
        if (isL1) {
            j = tid >> 1;
            Wp = (tid & 1) ? Wg2 : Wg1;
            bias = ((tid & 1) ? bg2 : bg1)[j];
        } else if (isL2) {
            j = (tid - 320) >> 1;
            Wp = ((tid & 1) ? Wg2 : Wg1) + LAY * LAY;
            bias = ((tid & 1) ? bg2 : bg1)[LAY + j];
        } else if (isAB) {
            j = (tid - 640) >> 1;
            Wp = (tid & 1) ? Wb : Wa;  od = HID;
            bias = ((tid & 1) ? bb : ba)[j];
        }
        if (Wp) { WR17(LOADW) }
    }
    __syncthreads();

    // ---------------- init: S0 = H0 @ Wh + bh ; norm_0 ; x-part ----------------
    float h = 0.f;                                   // even-AB threads' H-state register
    if (isAB && !(tid & 1)) {
        int j = (tid - 640) >> 1;
        float s = bh[j];
        for (int k = 0; k < STs; ++k) s += H0l[k] * Wh[k * HID + j];
        h = s;
        Hf[j] = s;
        ((_Float16*)LvX)[6 + j] = (_Float16)s;
    }
    if (tid == 1022) {
        float s = 0.f;
#pragma unroll
        for (int i = 0; i < 6; ++i) s += Xls[i] * Xls[i];
        float nv = sqrtf(s);
        float rn = rcp_fast(nv);
        nrm[0] = nv; rnr[0] = rn;
        LvX[0] = pack2(Xls[0]*rn, Xls[1]*rn);
        LvX[1] = pack2(Xls[2]*rn, Xls[3]*rn);
        LvX[2] = pack2(Xls[4]*rn, Xls[5]*rn);
    }
    __syncthreads();

    const float LOG2E = 1.4426950408889634f;

#pragma unroll 1
    for (int t = 0; t < Tt; ++t) {
        const int p = t & 1;
        // ---- P1: gated layer 1 ; proj Y[t-1] ; norm for t+1 ----
        if (isL1) {
            float s; DO_DOT(LvX, s); s += bias;
            float tn = tanh_fast(s);
            float to = __shfl_xor(tn, 1, 64);
            if (!(tid & 1)) ((_Float16*)LvB)[tid >> 1] = (_Float16)(tn * to);
        } else if (isPJ) {
            if (t > 0)
                do_proj(Hf, Wol, bol, out + ((size_t)n * Tt + (t - 1)) * OUTs, tid - 896);
        } else if (tid == 1022 && (t + 1) < Tt) {
            const float* xp = &Xls[(t + 1) * INs];
            float s = 0.f;
#pragma unroll
            for (int i = 0; i < 6; ++i) s += xp[i] * xp[i];
            float nv = sqrtf(s);
            nrm[(t + 1) & 1] = nv;
            rnr[(t + 1) & 1] = rcp_fast(nv);
        }
        __syncthreads();
        // ---- P2: gated layer 2 ; write x-part of LvX for t+1 ----
        if (isL2) {
            float s; DO_DOT(LvB, s); s += bias;
            float tn = tanh_fast(s);
            float to = __shfl_xor(tn, 1, 64);
            if (!(tid & 1)) ((_Float16*)LvC)[(tid - 320) >> 1] = (_Float16)(tn * to);
        } else if (tid == 1023 && (t + 1) < Tt) {
            const float* xp = &Xls[(t + 1) * INs];
            float rn = rnr[(t + 1) & 1];
            LvX[0] = pack2(xp[0]*rn, xp[1]*rn);
            LvX[1] = pack2(xp[2]*rn, xp[3]*rn);
            LvX[2] = pack2(xp[4]*rn, xp[5]*rn);
        }
        __syncthreads();
        // ---- P3: alpha/beta + H update (H state in even lane's register) ----
        if (isAB) {
            float s; DO_DOT(LvC, s); s += bias;
            float bown = tanh_fast(s);                 // odd lane: beta
            float beta = __shfl_xor(bown, 1, 64);      // even lane receives beta
            if (!(tid & 1)) {
                int j = (tid - 640) >> 1;
                float alpha = exp2_fast(s * LOG2E);    // even lane: alpha = exp(sA)
                float e = exp2_fast(-alpha * nrm[p] * LOG2E);
                h = e * (h - beta) + beta;
                Hf[j] = h;
                ((_Float16*)LvX)[6 + j] = (_Float16)h;
            }
        }
        __syncthreads();
    }
    // ---- epilogue: project Y[T-1] = final H ----
    if (isPJ)
        do_proj(Hf, Wol, bol, out + ((size_t)n * Tt + (Tt - 1)) * OUTs, tid - 896);
}

extern "C" void kernel_launch(void* const* d_in, const int* in_sizes, int n_in,
                              void* d_out, int out_size, void* d_ws, size_t ws_size,
                              hipStream_t stream) {
    const float* X   = (const float*)d_in[0];
    const float* H0  = (const float*)d_in[1];
    const float* Wg1 = (const float*)d_in[2];
    const float* bg1 = (const float*)d_in[3];
    const float* Wg2 = (const float*)d_in[4];
    const float* bg2 = (const float*)d_in[5];
    const float* Wa  = (const float*)d_in[6];
    const float* ba  = (const float*)d_in[7];
    const float* Wb  = (const float*)d_in[8];
    const float* bb  = (const float*)d_in[9];
    const float* Wh  = (const float*)d_in[10];
    const float* bh  = (const float*)d_in[11];
    const float* Wo  = (const float*)d_in[12];
    const float* bo  = (const float*)d_in[13];
    float* out = (float*)d_out;

    hipLaunchKernelGGL(lmsc_kernel, dim3(Nb), dim3(1024), 0, stream,
                       X, H0, Wg1, bg1, Wg2, bg2, Wa, ba, Wb, bb, Wh, bh, Wo, bo, out);
}

// Round 9
// 3402.251 us; speedup vs baseline: 1.0509x; 1.0509x over previous
//
#include <hip/hip_runtime.h>

// Problem constants (must match reference)
#define Nb   256
#define Tt   2048
#define INs  6
#define HID  128
#define STs  64
#define LAY  134   // INs + HID
#define OUTs 6
#define NDW  68    // padded dword count (f16x2 units); last dword is zero pad

typedef __fp16 f16x2 __attribute__((ext_vector_type(2)));
typedef __fp16 f16x4 __attribute__((ext_vector_type(4)));
typedef __fp16 f16x8 __attribute__((ext_vector_type(8)));

__device__ __forceinline__ float exp2_fast(float x) {
#if __has_builtin(__builtin_amdgcn_exp2f)
    return __builtin_amdgcn_exp2f(x);
#else
    return exp2f(x);
#endif
}
__device__ __forceinline__ float rcp_fast(float x) {
#if __has_builtin(__builtin_amdgcn_rcpf)
    return __builtin_amdgcn_rcpf(x);
#else
    return 1.0f / x;
#endif
}
// tanh(x) = 1 - 2/(exp2(2*log2e*x)+1); saturates correctly for |x| large
__device__ __forceinline__ float tanh_fast(float x) {
    float e = exp2_fast(x * 2.8853900817779268f);
    return 1.0f - 2.0f * rcp_fast(e + 1.0f);
}
// RTZ pack (activations only; weights use RNE casts)
__device__ __forceinline__ unsigned pack2(float a, float b) {
#if __has_builtin(__builtin_amdgcn_cvt_pkrtz)
    union { f16x2 h; unsigned u; } u;
    u.h = __builtin_amdgcn_cvt_pkrtz(a, b);
    return u.u;
#else
    union { f16x2 h; unsigned u; } u;
    u.h[0] = (__fp16)a; u.h[1] = (__fp16)b;
    return u.u;
#endif
}
// RNE pack for weights
__device__ __forceinline__ unsigned pack2w(float a, float b) {
    union { f16x2 h; unsigned u; } u;
    u.h[0] = (__fp16)a; u.h[1] = (__fp16)b;
    return u.u;
}
__device__ __forceinline__ float dot2p(unsigned av, f16x2 wv, float c) {
    union { unsigned u; f16x2 f; } ua; ua.u = av;
#if __has_builtin(__builtin_amdgcn_fdot2)
    return __builtin_amdgcn_fdot2(ua.f, wv, c, false);   // v_dot2_f32_f16
#else
    return c + (float)ua.f[0] * (float)wv[0] + (float)ua.f[1] * (float)wv[1];
#endif
}
__device__ __forceinline__ float dotdw(unsigned av, unsigned wv, float c) {
    union { unsigned u; f16x2 f; } uw; uw.u = wv;
    return dot2p(av, uw.f, c);
}

// streamed dot: 68 packed dwords of activation vs 68 packed dwords of LDS weights
__device__ __forceinline__ float stream_dot(const unsigned* act, const unsigned* wcol) {
    const uint4* a4 = (const uint4*)act;
    const uint4* w4 = (const uint4*)wcol;
    float a0 = 0.f, a1 = 0.f, a2 = 0.f, a3 = 0.f;
#pragma unroll
    for (int k = 0; k < 17; ++k) {
        uint4 av = a4[k], wv = w4[k];
        a0 = dotdw(av.x, wv.x, a0);
        a1 = dotdw(av.y, wv.y, a1);
        a2 = dotdw(av.z, wv.z, a2);
        a3 = dotdw(av.w, wv.w, a3);
    }
    return (a0 + a1) + (a2 + a3);
}

#define WR17(M) M(0) M(1) M(2) M(3) M(4) M(5) M(6) M(7) M(8) M(9) M(10) M(11) M(12) M(13) M(14) M(15) M(16)

#define DECLW(k) f16x8 w##k = {};
#define DECLP(k) f16x4 p##k = {};

// main gate column j, stride LAY; rows >= LAY zero-pad
#define LOADW(k) { \
    f16x8 tmp; \
    _Pragma("unroll") \
    for (int q = 0; q < 8; ++q) { \
        int r = 8 * (k) + q; \
        float f = (r < LAY) ? Wp[r * LAY + j] : 0.f; \
        tmp[q] = (__fp16)f; \
    } \
    w##k = tmp; \
}
// alpha/beta half-column: rows hb+4k+q of col u, stride HID
#define LOADP(k) { \
    f16x4 tmp; \
    _Pragma("unroll") \
    for (int q = 0; q < 4; ++q) { \
        int r = hb + 4 * (k) + q; \
        float f = (r < LAY) ? Wp3[r * HID + u] : 0.f; \
        tmp[q] = (__fp16)f; \
    } \
    p##k = tmp; \
}
#define DOTW(k) { \
    uint4 v = b4[k]; \
    a0 = dot2p(v.x, __builtin_shufflevector(w##k, w##k, 0, 1), a0); \
    a1 = dot2p(v.y, __builtin_shufflevector(w##k, w##k, 2, 3), a1); \
    a2 = dot2p(v.z, __builtin_shufflevector(w##k, w##k, 4, 5), a2); \
    a3 = dot2p(v.w, __builtin_shufflevector(w##k, w##k, 6, 7), a3); \
}
#define DOTP(k) { \
    uint2 v = c2[k]; \
    q0 = dot2p(v.x, __builtin_shufflevector(p##k, p##k, 0, 1), q0); \
    q1 = dot2p(v.y, __builtin_shufflevector(p##k, p##k, 2, 3), q1); \
}

// Thread roles (512 threads, 8 waves). Register budget at 512-thr blocks is
// ~124 VGPRs (proven round 5); per-thread weights here = 67 + 34 = 101 dwords.
//   G1 = [0,256):  P1 gate col: even->Wg1[0] col u, odd->Wg2[0] col u (u=tid>>1)
//                  P3: Wa col u, even rows [0,68), odd rows [68,134)
//   G2 = [256,512): same for layer 2 (Wg1[1]/Wg2[1]) and Wb
//   P1/P2 overhang (gate cols 128..133): streamed from LDS by 12 threads of the
//   idle group (G2 threads 256..267 in P1; G1 threads 0..11 in P2)
//   wave 5 (320..383): output projection, in P1's shadow
//   thread 500: next-step norm (P1 shadow); thread 1: x-part write (finalize)
__global__ __launch_bounds__(512, 2)
void lmsc_kernel(const float* __restrict__ X,  const float* __restrict__ H0,
                 const float* __restrict__ Wg1, const float* __restrict__ bg1,
                 const float* __restrict__ Wg2, const float* __restrict__ bg2,
                 const float* __restrict__ Wa,  const float* __restrict__ ba,
                 const float* __restrict__ Wb,  const float* __restrict__ bb,
                 const float* __restrict__ Wh,  const float* __restrict__ bh,
                 const float* __restrict__ Wo,  const float* __restrict__ bo,
                 float* __restrict__ out)
{
    __shared__ float Xls[Tt * INs];                 // 48 KB
    __shared__ unsigned OvW1[12][NDW];              // P1 overhang cols (f16x2)
    __shared__ unsigned OvW2[12][NDW];              // P2 overhang cols
    __shared__ alignas(16) unsigned LvX[NDW];       // [x/n (3dw) | H f16 (64dw) | pad]
    __shared__ alignas(16) unsigned LvB[NDW];       // layer-1 output
    __shared__ alignas(16) unsigned LvC[NDW];       // layer-2 output
    __shared__ float Hf[HID];                       // f32 H for projection
    __shared__ float Bbe[HID];                      // beta hop G2->G1
    __shared__ float H0l[STs];
    __shared__ float WolT[OUTs][HID];               // transposed Wo (bank-friendly)
    __shared__ float bol[OUTs];
    __shared__ float nrm[2], rnr[2];

    const int tid = threadIdx.x;
    const int n   = blockIdx.x;

    const bool G1  = tid < 256;
    const int  u   = (tid & 255) >> 1;   // column / pair index
    const int  odd = tid & 1;

    // ---------------- stage X row (coalesced float4) ----------------
    {
        const float4* Xg  = (const float4*)(X + (size_t)n * (Tt * INs));
        float4*       Xl4 = (float4*)Xls;
        for (int i = tid; i < (Tt * INs) / 4; i += 512) Xl4[i] = Xg[i];
    }
    if (tid < STs) H0l[tid] = H0[n * STs + tid];
    // WolT[o][l] = Wo[l][o]
    for (int i = tid; i < OUTs * HID; i += 512) {
        int o = i / HID, l2 = i % HID;
        WolT[o][l2] = Wo[l2 * OUTs + o];
    }
    if (tid < OUTs) bol[tid] = bo[tid];
    if (tid == 30) { LvX[NDW-1] = 0u; LvB[NDW-1] = 0u; LvC[NDW-1] = 0u; }
    // overhang columns 128..133 of each gate matrix -> LDS (f16 RNE)
    if (tid >= 32 && tid < 56) {
        int i  = tid - 32;
        int L  = i / 12, s9 = i % 12, pp = s9 >> 1, mt = s9 & 1;
        const float* src = (mt ? Wg2 : Wg1) + L * LAY * LAY;
        unsigned* dst = L ? OvW2[s9] : OvW1[s9];
        for (int d = 0; d < 67; ++d)
            dst[d] = pack2w(src[(2*d) * LAY + 128 + pp], src[(2*d+1) * LAY + 128 + pp]);
        dst[67] = 0u;
    }

    // ------- weights -> named vector registers (67 + 34 dwords) -------
    WR17(DECLW)
    WR17(DECLP)
    float breg, pb;
    {
        const float* Wp = (odd ? Wg2 : Wg1) + (G1 ? 0 : LAY * LAY);
        const int j = u;
        WR17(LOADW)
        breg = (odd ? bg2 : bg1)[(G1 ? 0 : LAY) + j];
        const float* Wp3 = G1 ? Wa : Wb;
        const int hb = odd ? 68 : 0;
        WR17(LOADP)
        pb = (G1 ? ba : bb)[u];
    }
    // streamer biases
    float sb = 0.f;
    if (tid >= 256 && tid < 268) {
        int s9 = tid - 256;
        sb = ((s9 & 1) ? bg2 : bg1)[128 + (s9 >> 1)];
    } else if (tid < 12) {
        sb = (odd ? bg2 : bg1)[LAY + 128 + (tid >> 1)];
    }
    __syncthreads();

    // ---------------- init: S0 = H0 @ Wh + bh ; norm_0 ----------------
    float h = 0.f, s3 = 0.f;
    if (G1 && !odd) {
        float s = bh[u];
        for (int k = 0; k < STs; ++k) s += H0l[k] * Wh[k * HID + u];
        h = s;
        Hf[u] = s;
        ((__fp16*)LvX)[6 + u] = (__fp16)s;
    }
    if (tid == 500) {
        float s = 0.f;
#pragma unroll
        for (int i = 0; i < 6; ++i) s += Xls[i] * Xls[i];
        float nv = sqrtf(s);
        nrm[0] = nv; rnr[0] = rcp_fast(nv);
    }
    __syncthreads();
    if (tid == 1) {
        float rn = rnr[0];
        LvX[0] = pack2(Xls[0]*rn, Xls[1]*rn);
        LvX[1] = pack2(Xls[2]*rn, Xls[3]*rn);
        LvX[2] = pack2(Xls[4]*rn, Xls[5]*rn);
    }
    __syncthreads();

    const float LOG2E = 1.4426950408889634f;

#pragma unroll 1
    for (int t = 0; t < Tt; ++t) {
        // ---- P1: gate layer 1 (G1) ; overhang stream ; proj Y[t-1] ; next norm ----
        if (G1) {
            const uint4* b4 = (const uint4*)LvX;
            float a0 = 0.f, a1 = 0.f, a2 = 0.f, a3 = 0.f;
            WR17(DOTW)
            float s  = ((a0 + a1) + (a2 + a3)) + breg;
            float tn = tanh_fast(s);
            float to = __shfl_xor(tn, 1, 64);
            if (!odd) ((__fp16*)LvB)[u] = (__fp16)(tn * to);
        } else if (tid < 268) {                      // 256..267: P1 overhang
            int s9 = tid - 256;
            float sd = stream_dot(LvX, OvW1[s9]) + sb;
            float tn = tanh_fast(sd);
            float to = __shfl_xor(tn, 1, 64);
            if (!odd) ((__fp16*)LvB)[128 + (s9 >> 1)] = (__fp16)(tn * to);
        } else if (tid >= 320 && tid < 384) {        // wave 5: projection of Y[t-1]
            if (t > 0) {
                int l = tid - 320;
                float hA = Hf[2*l], hB = Hf[2*l+1];
                float r0 = hA*WolT[0][2*l] + hB*WolT[0][2*l+1];
                float r1 = hA*WolT[1][2*l] + hB*WolT[1][2*l+1];
                float r2 = hA*WolT[2][2*l] + hB*WolT[2][2*l+1];
                float r3 = hA*WolT[3][2*l] + hB*WolT[3][2*l+1];
                float r4 = hA*WolT[4][2*l] + hB*WolT[4][2*l+1];
                float r5 = hA*WolT[5][2*l] + hB*WolT[5][2*l+1];
#pragma unroll
                for (int k = 1; k < 64; k <<= 1) {
                    r0 += __shfl_xor(r0, k, 64); r1 += __shfl_xor(r1, k, 64);
                    r2 += __shfl_xor(r2, k, 64); r3 += __shfl_xor(r3, k, 64);
                    r4 += __shfl_xor(r4, k, 64); r5 += __shfl_xor(r5, k, 64);
                }
                if (l == 0) {
                    float* op = out + ((size_t)n * Tt + (t - 1)) * OUTs;
                    op[0] = r0 + bol[0]; op[1] = r1 + bol[1]; op[2] = r2 + bol[2];
                    op[3] = r3 + bol[3]; op[4] = r4 + bol[4]; op[5] = r5 + bol[5];
                }
            }
        } else if (tid == 500 && (t + 1) < Tt) {     // next-step norm
            const float* xp = &Xls[(t + 1) * INs];
            float s = 0.f;
#pragma unroll
            for (int i = 0; i < 6; ++i) s += xp[i] * xp[i];
            float nv = sqrtf(s);
            nrm[(t + 1) & 1] = nv;
            rnr[(t + 1) & 1] = rcp_fast(nv);
        }
        __syncthreads();
        // ---- P2: gate layer 2 (G2) ; overhang stream (G1 threads 0..11) ----
        if (!G1) {
            const uint4* b4 = (const uint4*)LvB;
            float a0 = 0.f, a1 = 0.f, a2 = 0.f, a3 = 0.f;
            WR17(DOTW)
            float s  = ((a0 + a1) + (a2 + a3)) + breg;
            float tn = tanh_fast(s);
            float to = __shfl_xor(tn, 1, 64);
            if (!odd) ((__fp16*)LvC)[u] = (__fp16)(tn * to);
        } else if (tid < 12) {
            float sd = stream_dot(LvB, OvW2[tid]) + sb;
            float tn = tanh_fast(sd);
            float to = __shfl_xor(tn, 1, 64);
            if (!odd) ((__fp16*)LvC)[128 + (tid >> 1)] = (__fp16)(tn * to);
        }
        __syncthreads();
        // ---- P3: alpha/beta half-column dots (all 512 threads) ----
        {
            const uint2* c2 = (const uint2*)LvC + (odd ? 17 : 0);
            float q0 = 0.f, q1 = 0.f;
            WR17(DOTP)
            float pd = q0 + q1;
            pd += __shfl_xor(pd, 1, 64);
            if (!odd) {
                s3 = pd + pb;
                if (!G1) Bbe[u] = tanh_fast(s3);     // beta -> LDS hop
            }
        }
        __syncthreads();
        // ---- finalize: H update (G1-evens own h[u]) ; x-part for t+1 ----
        if (G1 && !odd) {
            float alpha = exp2_fast(s3 * LOG2E);
            float beta  = Bbe[u];
            float e = exp2_fast(-alpha * nrm[t & 1] * LOG2E);
            h = e * (h - beta) + beta;
            Hf[u] = h;
            ((__fp16*)LvX)[6 + u] = (__fp16)h;
        } else if (tid == 1 && (t + 1) < Tt) {
            const float* xp = &Xls[(t + 1) * INs];
            float rn = rnr[(t + 1) & 1];
            LvX[0] = pack2(xp[0]*rn, xp[1]*rn);
            LvX[1] = pack2(xp[2]*rn, xp[3]*rn);
            LvX[2] = pack2(xp[4]*rn, xp[5]*rn);
        }
        __syncthreads();
    }
    // ---- epilogue: project Y[T-1] = final H ----
    if (tid >= 320 && tid < 384) {
        int l = tid - 320;
        float hA = Hf[2*l], hB = Hf[2*l+1];
        float r0 = hA*WolT[0][2*l] + hB*WolT[0][2*l+1];
        float r1 = hA*WolT[1][2*l] + hB*WolT[1][2*l+1];
        float r2 = hA*WolT[2][2*l] + hB*WolT[2][2*l+1];
        float r3 = hA*WolT[3][2*l] + hB*WolT[3][2*l+1];
        float r4 = hA*WolT[4][2*l] + hB*WolT[4][2*l+1];
        float r5 = hA*WolT[5][2*l] + hB*WolT[5][2*l+1];
#pragma unroll
        for (int k = 1; k < 64; k <<= 1) {
            r0 += __shfl_xor(r0, k, 64); r1 += __shfl_xor(r1, k, 64);
            r2 += __shfl_xor(r2, k, 64); r3 += __shfl_xor(r3, k, 64);
            r4 += __shfl_xor(r4, k, 64); r5 += __shfl_xor(r5, k, 64);
        }
        if (l == 0) {
            float* op = out + ((size_t)n * Tt + (Tt - 1)) * OUTs;
            op[0] = r0 + bol[0]; op[1] = r1 + bol[1]; op[2] = r2 + bol[2];
            op[3] = r3 + bol[3]; op[4] = r4 + bol[4]; op[5] = r5 + bol[5];
        }
    }
}

extern "C" void kernel_launch(void* const* d_in, const int* in_sizes, int n_in,
                              void* d_out, int out_size, void* d_ws, size_t ws_size,
                              hipStream_t stream) {
    const float* X   = (const float*)d_in[0];
    const float* H0  = (const float*)d_in[1];
    const float* Wg1 = (const float*)d_in[2];
    const float* bg1 = (const float*)d_in[3];
    const float* Wg2 = (const float*)d_in[4];
    const float* bg2 = (const float*)d_in[5];
    const float* Wa  = (const float*)d_in[6];
    const float* ba  = (const float*)d_in[7];
    const float* Wb  = (const float*)d_in[8];
    const float* bb  = (const float*)d_in[9];
    const float* Wh  = (const float*)d_in[10];
    const float* bh  = (const float*)d_in[11];
    const float* Wo  = (const float*)d_in[12];
    const float* bo  = (const float*)d_in[13];
    float* out = (float*)d_out;

    hipLaunchKernelGGL(lmsc_kernel, dim3(Nb), dim3(512), 0, stream,
                       X, H0, Wg1, bg1, Wg2, bg2, Wa, ba, Wb, bb, Wh, bh, Wo, bo, out);
}